// Round 7
// baseline (365.861 us; speedup 1.0000x reference)
//
#include <hip/hip_runtime.h>
#include <hip/hip_bf16.h>

#define DEVI __device__ __forceinline__

constexpr int B_   = 8;
constexpr int L_   = 4097;
constexpr int MTOT = B_ * L_;          // 32776 tokens
constexpr int DH   = 384;              // d_half
constexpr int NS   = 16;               // d_state
constexpr int CH   = 22;               // scan chunk (r15: 33->22, 4488 blocks ->
                                       // 35 waves/CU; summaries 39MB fit d_out)
constexpr int NCH  = (L_ + CH - 1) / CH;  // 187 chunks (last has 5 tokens)

typedef __bf16 bf16x8 __attribute__((ext_vector_type(8)));
typedef float  f32x4  __attribute__((ext_vector_type(4)));

DEVI float bl(unsigned v) { return __uint_as_float(v << 16); }          // low bf16
DEVI float bh(unsigned v) { return __uint_as_float(v & 0xffff0000u); }  // high bf16
DEVI float bf(const __hip_bfloat16 x) { return __bfloat162float(x); }
DEVI unsigned short f2bu(float x) {
  __hip_bfloat16 b = __float2bfloat16(x);
  return *(unsigned short*)&b;
}
DEVI float u16f(const uint4& u, int j) {   // element j (0..7) of 8 packed bf16
  const unsigned w = (&u.x)[j >> 1];
  return (j & 1) ? bh(w) : bl(w);
}
// fast softplus: 2 HW transcendentals vs log1pf's ~30-instr libm sequence
DEVI float softplus_f(float x) {
  return (x > 20.f) ? x : __logf(1.f + __expf(x));
}

// global -> LDS direct (16B per lane). LDS dest must be wave-uniform + lane*16.
DEVI void gld16(const __hip_bfloat16* g, __hip_bfloat16* l) {
  __builtin_amdgcn_global_load_lds(
      (const __attribute__((address_space(1))) void*)g,
      (__attribute__((address_space(3))) void*)l, 16, 0, 0);
}

// ---------------------------------------------------------------------------
// dtype detector; flag[1] = geometric-A structure flag.
// ---------------------------------------------------------------------------
__global__ void flag_k(const void* hs, int* flagp) {
  if (threadIdx.x == 0 && blockIdx.x == 0) {
    const unsigned short* u = (const unsigned short*)hs;
    int ok = 1;
    for (int i = 0; i < 8; ++i) {
      const unsigned short v = u[2 * i];
      const int e = (v >> 7) & 0xFF;
      if (!(v == 0 || (e >= 100 && e <= 140))) ok = 0;
    }
    flagp[0] = ok;
    flagp[1] = 1;
  }
}

// ---------------------------------------------------------------------------
// a2prep_k: a2[d][n] = -log2(e)*exp(A_log[d][n]) fp32 + geometric check.
// ---------------------------------------------------------------------------
__global__ void a2prep_k(const void* __restrict__ alog, float* __restrict__ a2fo,
                         int* flagp) {
  const int d = threadIdx.x;             // 384 threads, one d each
  const int f = flagp[0];
  float a2[16];
#pragma unroll
  for (int n = 0; n < 16; ++n) {
    const float v = f ? bf(((const __hip_bfloat16*)alog)[d * 16 + n])
                      : ((const float*)alog)[d * 16 + n];
    a2[n] = -1.4426950408889634f * __expf(v);
    a2fo[d * 16 + n] = a2[n];
  }
  int ok = 1;
#pragma unroll
  for (int n = 1; n < 16; ++n) {
    const float ref = (float)(n + 1) * a2[0];
    if (fabsf(a2[n] - ref) > 1e-3f * fabsf(ref)) ok = 0;
  }
  if (!ok) atomicAnd(&flagp[1], 0);
}

// ---------------------------------------------------------------------------
// perm normalizer: int64 storage has all odd int32 words zero (values<4096).
// ---------------------------------------------------------------------------
__global__ void perm_k(const int* p0, const int* p1, int* d0, int* d1) {
  __shared__ int s_or;
  const int* src = blockIdx.x ? p1 : p0;
  int*       dst = blockIdx.x ? d1 : d0;
  if (threadIdx.x == 0) s_or = 0;
  __syncthreads();
  int loc = 0;
  for (int i = threadIdx.x; i < 2048; i += 1024) loc |= src[2 * i + 1];
  atomicOr(&s_or, loc);
  __syncthreads();
  const bool is64 = (s_or == 0);
  for (int j = threadIdx.x; j < 4096; j += 1024)
    dst[j] = is64 ? (int)((const long long*)src)[j] : src[j];
}

// ---------------------------------------------------------------------------
// fused normalization of weight tensors to bf16 (one launch)
// ---------------------------------------------------------------------------
struct NormSet { const void* src[8]; void* dst[8]; int n[8]; };
__global__ void norm_all(NormSet s, const int* flagp) {
  const int idx = blockIdx.x * 256 + threadIdx.x;
  const int f = flagp[0];
#pragma unroll
  for (int t = 0; t < 8; ++t) {
    if (idx < s.n[t]) {
      __hip_bfloat16* d = (__hip_bfloat16*)s.dst[t];
      if (f) d[idx] = ((const __hip_bfloat16*)s.src[t])[idx];
      else   d[idx] = __float2bfloat16(((const float*)s.src[t])[idx]);
    }
  }
}

// ---------------------------------------------------------------------------
// Wcomb bf16 (512 x 384): rows 0..383 = dt_proj_w @ x_proj_w[0:24],
// rows 384..415 = x_proj_w[24:56] (B then C), rows 416..511 = 0.
// ---------------------------------------------------------------------------
__global__ void prep_k(const __hip_bfloat16* __restrict__ dtw,
                       const __hip_bfloat16* __restrict__ xw,
                       __hip_bfloat16* __restrict__ wcomb) {
  const int idx = blockIdx.x * 256 + threadIdx.x;
  if (idx >= 512 * 384) return;
  const int n = idx / 384, k = idx - n * 384;
  float v = 0.f;
  if (n < 384) {
#pragma unroll
    for (int r = 0; r < 24; ++r) v += bf(dtw[n * 24 + r]) * bf(xw[r * 384 + k]);
  } else if (n < 416) {
    v = bf(xw[(24 + n - 384) * 384 + k]);
  }
  wcomb[idx] = __float2bfloat16(v);
}

// ---------------------------------------------------------------------------
// cvt_k: fused perm-gather + dtype-normalize of hidden_states into bf16 hsb.
// ---------------------------------------------------------------------------
__global__ void cvt_k(const void* __restrict__ hs, __hip_bfloat16* __restrict__ dst,
                      const int* __restrict__ gidx, const int* __restrict__ flagp) {
  const int idx = blockIdx.x * 256 + threadIdx.x;
  if (idx >= MTOT * 48) return;
  const int j = idx % 48;        // 8-elem group within row
  const int r = idx / 48;        // destination (reordered) token row
  const int b = r / L_, t = r - b * L_;
  const int src = b * L_ + (t == 0 ? 0 : 1 + gidx[t - 1]);
  uint4 o;
  if (flagp[0]) {
    o = *(const uint4*)((const __hip_bfloat16*)hs + (size_t)src * 384 + j * 8);
  } else {
    const float* f = (const float*)hs + (size_t)src * 384 + j * 8;
    const float4 f0 = *(const float4*)f;
    const float4 f1 = *(const float4*)(f + 4);
    o.x = f2bu(f0.x) | ((unsigned)f2bu(f0.y) << 16);
    o.y = f2bu(f0.z) | ((unsigned)f2bu(f0.w) << 16);
    o.z = f2bu(f1.x) | ((unsigned)f2bu(f1.y) << 16);
    o.w = f2bu(f1.z) | ((unsigned)f2bu(f1.w) << 16);
  }
  *(uint4*)(dst + (size_t)r * 384 + j * 8) = o;
}

// ---------------------------------------------------------------------------
// MFMA GEMM: 128x128 tile, K=384 = 6 x BK64, staging via global_load_lds w=16
// into [kh][128][32] LDS layout. Epilogue via LDS-transposed 2-pass coalesced
// 16B stores. Bijective XCD-contiguous tile remap.
// ---------------------------------------------------------------------------
template<int GATHER, int EPI>
__global__ __launch_bounds__(256, 3)
void gemm_k(const __hip_bfloat16* __restrict__ A, const __hip_bfloat16* __restrict__ W,
            void* __restrict__ e0, void* __restrict__ e1,
            const __hip_bfloat16* __restrict__ bias,
            const int* __restrict__ gidx, const int* __restrict__ flagp,
            int M, int N)
{
  __shared__ __align__(16) char smem[36864];   // staging 32KB | lT 18.4/36.9KB
  __hip_bfloat16* lA = (__hip_bfloat16*)smem;  // [2][128][32] bf16
  __hip_bfloat16* lB = lA + 2 * 128 * 32;
  const int tid  = threadIdx.x;
  const int lane = tid & 63;
  const int wv   = tid >> 6;
  const int wm   = wv >> 1, wn = wv & 1;
  const int lrow = lane & 15, quad = lane >> 4;
  const int fbf  = flagp[0];              // 1 = bf16 external storage

  const int NT = gridDim.x;
  const int nblocks = NT * (int)gridDim.y;
  const int id = blockIdx.y * NT + blockIdx.x;
  const int q8 = nblocks >> 3, r8 = nblocks & 7;
  const int xcd = id & 7, slot = id >> 3;
  const int nid = (xcd < r8 ? xcd * (q8 + 1)
                            : r8 * (q8 + 1) + (xcd - r8) * q8) + slot;
  const int mt = nid / NT, nt = nid - mt * NT;

  // wave whose whole 64-col band is Wcomb zero-pad: skip fragment+MFMA work
  const bool live = !(EPI == 1 && nt * 128 + wn * 64 >= 416);

  // staging map: flat 16B slot s -> (kh = s>>9, row = (s>>2)&127, c = s&3);
  // LDS dest linear in s (gld_lds constraint); global src permuted to match.
  const __hip_bfloat16* aSrc[4];
  const __hip_bfloat16* bSrc[4];
  __hip_bfloat16* aDst[4];
  __hip_bfloat16* bDst[4];
#pragma unroll
  for (int p = 0; p < 4; ++p) {
    const int s   = p * 256 + tid;
    const int kh  = s >> 9;
    const int row = (s >> 2) & 127;
    const int kc  = kh * 32 + (s & 3) * 8;   // K offset within BK=64
    int r = mt * 128 + row;
    if (r >= M) r = M - 1;                   // tail tile: duplicate a valid row
    int src;
    if (GATHER) { const int b = r / L_, t = r - b * L_;
                  src = b * L_ + (t == 0 ? 0 : 1 + gidx[t - 1]); }
    else        { src = r; }
    aSrc[p] = A + (size_t)src * 384 + kc;
    bSrc[p] = W + (size_t)(nt * 128 + row) * 384 + kc;
    aDst[p] = &lA[s * 8];
    bDst[p] = &lB[s * 8];
  }

  f32x4 acc[4][4] = {};

#pragma unroll
  for (int kt = 0; kt < 6; ++kt) {         // K = 6 * 64
    __syncthreads();                       // WAR: prior ds_reads done
#pragma unroll
    for (int p = 0; p < 4; ++p) gld16(aSrc[p] + kt * 64, aDst[p]);
#pragma unroll
    for (int p = 0; p < 4; ++p) gld16(bSrc[p] + kt * 64, bDst[p]);
    __syncthreads();                       // staged data visible
    if (live) {
#pragma unroll
      for (int kh = 0; kh < 2; ++kh) {
        bf16x8 af[4], bfr[4];
#pragma unroll
        for (int i = 0; i < 4; ++i)
          af[i] = *reinterpret_cast<const bf16x8*>(
              &lA[kh * 4096 + (wm * 64 + i * 16 + lrow) * 32 + quad * 8]);
#pragma unroll
        for (int j = 0; j < 4; ++j)
          bfr[j] = *reinterpret_cast<const bf16x8*>(
              &lB[kh * 4096 + (wn * 64 + j * 16 + lrow) * 32 + quad * 8]);
#pragma unroll
        for (int i = 0; i < 4; ++i)
#pragma unroll
          for (int j = 0; j < 4; ++j)
            acc[i][j] = __builtin_amdgcn_mfma_f32_16x16x32_bf16(af[i], bfr[j], acc[i][j], 0, 0, 0);
      }
    }
  }

  // ---- epilogue (acc[i][j][rg] = C[row=quad*4+rg(+i*16+wm*64)][col=lrow(+j*16+wn*64)])
  const int r0c = mt * 128;
  if (EPI == 1 && nt == 3) {
    // scalar B/C path (cols 384..415, fp32)
#pragma unroll
    for (int i = 0; i < 4; ++i) {
      const int row0 = r0c + wm * 64 + i * 16 + quad * 4;
#pragma unroll
      for (int j = 0; j < 4; ++j) {
        const int col = 384 + wn * 64 + j * 16 + lrow;
        if (col >= 416) continue;
#pragma unroll
        for (int rg = 0; rg < 4; ++rg) {
          const int r = row0 + rg;
          if (r >= M) continue;
          ((float*)e1)[(size_t)r * 32 + (col - 384)] = acc[i][j][rg];
        }
      }
    }
  } else if (EPI == 2 && !fbf) {
    // fp32 out: 2-pass LDS transpose ([128][72] f32), coalesced 16B stores
    float* lT = (float*)smem;
#pragma unroll
    for (int h = 0; h < 2; ++h) {
      __syncthreads();
      if (wn == h) {
#pragma unroll
        for (int i = 0; i < 4; ++i)
#pragma unroll
          for (int j = 0; j < 4; ++j)
#pragma unroll
            for (int rg = 0; rg < 4; ++rg)
              lT[(wm * 64 + i * 16 + quad * 4 + rg) * 72 + j * 16 + lrow] = acc[i][j][rg];
      }
      __syncthreads();
#pragma unroll
      for (int p = 0; p < 8; ++p) {
        const int ch = p * 256 + tid;      // 2048 x 16B chunks
        const int row = ch >> 4, c4 = (ch & 15) * 4;
        const int r = r0c + row;
        if (r < M) {
          const float4 v = *(const float4*)&lT[row * 72 + c4];
          *(float4*)((float*)e0 + (size_t)r * 384 + nt * 128 + h * 64 + c4) = v;
        }
      }
    }
  } else {
    // bf16: 2-pass LDS transpose ([128][72] bf16), coalesced 16B stores.
    // EPI=0 plain; EPI=1 nt<3 softplus+bias; EPI=2 fbf plain.
    __hip_bfloat16* lT = (__hip_bfloat16*)smem;
#pragma unroll
    for (int h = 0; h < 2; ++h) {
      __syncthreads();
      if (wn == h) {
        float bj[4] = {};
        if (EPI == 1) {
#pragma unroll
          for (int j = 0; j < 4; ++j)
            bj[j] = bf(bias[nt * 128 + h * 64 + j * 16 + lrow]);
        }
#pragma unroll
        for (int i = 0; i < 4; ++i)
#pragma unroll
          for (int j = 0; j < 4; ++j)
#pragma unroll
            for (int rg = 0; rg < 4; ++rg) {
              float v = acc[i][j][rg];
              if (EPI == 1) v = softplus_f(v + bj[j]);
              lT[(wm * 64 + i * 16 + quad * 4 + rg) * 72 + j * 16 + lrow] =
                  __float2bfloat16(v);
            }
      }
      __syncthreads();
#pragma unroll
      for (int p = 0; p < 4; ++p) {
        const int ch = p * 256 + tid;      // 1024 x 16B chunks
        const int row = ch >> 3, c8 = (ch & 7) * 8;
        const int r = r0c + row;
        if (r < M) {
          const uint4 v = *(const uint4*)&lT[row * 72 + c8];
          const int g = nt * 128 + h * 64 + c8;
          __hip_bfloat16* dst = (EPI == 0 && g >= 384)
                ? (__hip_bfloat16*)e1 + (size_t)r * 384 + (g - 384)
                : (__hip_bfloat16*)e0 + (size_t)r * 384 + g;
          *(uint4*)dst = v;
        }
      }
    }
  }
}

// ---------------------------------------------------------------------------
// depthwise conv k=4 (taps t-1..t+2) + silu on x half; 8 channels/thread.
// ---------------------------------------------------------------------------
__global__ void convx_k(const __hip_bfloat16* __restrict__ xh,
                        const __hip_bfloat16* __restrict__ cxw,
                        __hip_bfloat16* __restrict__ xc) {
  const int idx = blockIdx.x * 256 + threadIdx.x;
  if (idx >= MTOT * 48) return;
  const int g  = idx % 48;       // channel group (8 ch)
  const int rg = idx / 48;       // token row
  const int t  = rg % L_;
  const int c0 = g * 8;
  uint4 wv[4];                   // weights: channels c0..c0+7 x 4 taps
#pragma unroll
  for (int p = 0; p < 4; ++p) wv[p] = *(const uint4*)(cxw + c0 * 4 + p * 8);
  float acc[8] = {};
#pragma unroll
  for (int k = 0; k < 4; ++k) {
    const int tt = t + k - 1;
    if (tt < 0 || tt >= L_) continue;
    const uint4 u = *(const uint4*)(xh + (size_t)(rg + k - 1) * 384 + c0);
#pragma unroll
    for (int j = 0; j < 8; ++j) {
      const int e = j * 4 + k;                      // weight flat element
      acc[j] += u16f(wv[e >> 3], e & 7) * u16f(u, j);
    }
  }
  uint4 o;
#pragma unroll
  for (int p = 0; p < 4; ++p) {
    const float s0 = acc[2 * p]     / (1.f + __expf(-acc[2 * p]));
    const float s1 = acc[2 * p + 1] / (1.f + __expf(-acc[2 * p + 1]));
    (&o.x)[p] = f2bu(s0) | ((unsigned)f2bu(s1) << 16);
  }
  *(uint4*)(xc + (size_t)rg * 384 + c0) = o;
}

// ---------------------------------------------------------------------------
// scan phase 1 (r15: summary-only). Per (b, chunk, d): run the h-recurrence
// with h0=0, emit ONLY sdt_chunk (1 float) + h_end (16). No y computation,
// no y write (the old y_local+corr split cost a 50MB yl round-trip and
// duplicated the power tree; scan3 now runs the true recurrence instead).
// ---------------------------------------------------------------------------
__global__ __launch_bounds__(128)
void scan1_k(const __hip_bfloat16* __restrict__ dt, const float* __restrict__ bc,
             const __hip_bfloat16* __restrict__ xc,
             const float* __restrict__ a2f,
             float* __restrict__ sdtc, float* __restrict__ hend,
             const int* __restrict__ flagp)
{
  __shared__ __align__(16) float lB[CH * 16];
  const int blk = blockIdx.x;
  const int dt3 = blk % 3;
  const int c   = (blk / 3) % NCH;
  const int b   = blk / (3 * NCH);
  const int d   = dt3 * 128 + threadIdx.x;
  const int t0  = c * CH;
  const int r0  = b * L_ + t0;
  const int tmax = (L_ - t0 < CH) ? (L_ - t0) : CH;
  for (int i = threadIdx.x; i < tmax * 16; i += 128)
    lB[i] = bc[(size_t)r0 * 32 + (i >> 4) * 32 + (i & 15)];
  __syncthreads();

  float h[16];
#pragma unroll
  for (int n = 0; n < 16; ++n) h[n] = 0.f;
  float sdt = 0.f;
  const size_t hbase = ((size_t)(c * 8 + b) * 16) * 384 + d;

  if (flagp[1]) {                          // geometric A: a2[n] = (n+1)*a2b
    const float a2b = a2f[d * 16];
    for (int tt = 0; tt < tmax; ++tt) {
      const size_t r = (size_t)(r0 + tt);
      const float dtv = bf(dt[r * 384 + d]);
      const float xv  = bf(xc[r * 384 + d]);
      sdt += dtv;
      const float dtx = dtv * xv;
      float pw[17];
      pw[1] = exp2f(dtv * a2b);
#pragma unroll
      for (int n = 2; n <= 16; ++n) pw[n] = pw[n >> 1] * pw[n - (n >> 1)];
      float4 bq[4];
#pragma unroll
      for (int q = 0; q < 4; ++q) bq[q] = *(const float4*)&lB[tt * 16 + q * 4];
#pragma unroll
      for (int n = 0; n < 16; ++n)
        h[n] = h[n] * pw[n + 1] + dtx * (&bq[n >> 2].x)[n & 3];
    }
  } else {                                 // generic A fallback
    float a2[16];
#pragma unroll
    for (int n = 0; n < 16; ++n) a2[n] = a2f[d * 16 + n];
    for (int tt = 0; tt < tmax; ++tt) {
      const size_t r = (size_t)(r0 + tt);
      const float dtv = bf(dt[r * 384 + d]);
      const float xv  = bf(xc[r * 384 + d]);
      sdt += dtv;
      const float dtx = dtv * xv;
      float4 bq[4];
#pragma unroll
      for (int q = 0; q < 4; ++q) bq[q] = *(const float4*)&lB[tt * 16 + q * 4];
#pragma unroll
      for (int n = 0; n < 16; ++n)
        h[n] = h[n] * exp2f(dtv * a2[n]) + dtx * (&bq[n >> 2].x)[n & 3];
    }
  }
  sdtc[(size_t)(c * 8 + b) * 384 + d] = sdt;
#pragma unroll
  for (int n = 0; n < 16; ++n) hend[hbase + n * 384] = h[n];
}

// ---------------------------------------------------------------------------
// scan phase 2: cross-chunk scan per (b,d,n). Chunk decay recomputed from
// sdt_chunk (P = exp2(sdt*a2[n]) -- exact for both geometric and generic A).
// h_end is rewritten IN PLACE with h_start.
// ---------------------------------------------------------------------------
__global__ void scan2_k(const float* __restrict__ sdtc, float* __restrict__ hh,
                        const float* __restrict__ a2f) {
  const int tid = blockIdx.x * 256 + threadIdx.x;   // 49152 total
  const int d = tid % 384;
  const int n = (tid / 384) & 15;
  const int b = tid / 6144;
  const float a2n = a2f[d * 16 + n];
  float H = 0.f;
#pragma unroll 4
  for (int c = 0; c < NCH; ++c) {
    const size_t idx = ((size_t)(c * 8 + b) * 16 + n) * 384 + d;
    const float sdt = sdtc[(size_t)(c * 8 + b) * 384 + d];
    const float he = hh[idx];
    hh[idx] = H;
    H = exp2f(sdt * a2n) * H + he;
  }
}

// ---------------------------------------------------------------------------
// scan phase 3 (r15: true recurrence). h initialized from h_start; per t:
// h update + y = C.h + D*x, fused z-conv + silu gate. Writes IN PLACE over
// dt (dtyg). Replaces the old y_local+corr scheme (saves the yl round-trip).
// ---------------------------------------------------------------------------
__global__ __launch_bounds__(128)
void scan3_k(__hip_bfloat16* dtyg, const float* __restrict__ bc,
             const __hip_bfloat16* __restrict__ xc,
             const __hip_bfloat16* __restrict__ zh,
             const __hip_bfloat16* __restrict__ czw,
             const __hip_bfloat16* __restrict__ dpar,
             const float* __restrict__ a2f,
             const float* __restrict__ hstart,
             const int* __restrict__ flagp)
{
  __shared__ __align__(16) float lBC[CH * 32];
  const int blk = blockIdx.x;
  const int dt3 = blk % 3;
  const int c   = (blk / 3) % NCH;
  const int b   = blk / (3 * NCH);
  const int d   = dt3 * 128 + threadIdx.x;
  const int t0  = c * CH;
  const int r0  = b * L_ + t0;
  const int tmax = (L_ - t0 < CH) ? (L_ - t0) : CH;
  for (int i = threadIdx.x; i < tmax * 32; i += 128) lBC[i] = bc[(size_t)r0 * 32 + i];
  __syncthreads();

  float h[16];
  const size_t hbase = ((size_t)(c * 8 + b) * 16) * 384 + d;
#pragma unroll
  for (int n = 0; n < 16; ++n) h[n] = hstart[hbase + n * 384];
  const float Dd = bf(dpar[d]);
  float cw[4];
#pragma unroll
  for (int k = 0; k < 4; ++k) cw[k] = bf(czw[d * 4 + k]);

  float zm1 = (t0 - 1 >= 0) ? bf(zh[(size_t)(r0 - 1) * 384 + d]) : 0.f;
  float z0  = bf(zh[(size_t)r0 * 384 + d]);
  float zp1 = (t0 + 1 < L_) ? bf(zh[(size_t)(r0 + 1) * 384 + d]) : 0.f;

  if (flagp[1]) {                          // geometric A fast path
    const float a2b = a2f[d * 16];
    for (int tt = 0; tt < tmax; ++tt) {
      const int t = t0 + tt;
      const size_t r = (size_t)(r0 + tt);
      const float zp2 = (t + 2 < L_) ? bf(zh[(r + 2) * 384 + d]) : 0.f;
      const float dtv = bf(dtyg[r * 384 + d]);
      const float xv  = bf(xc[r * 384 + d]);
      const float dtx = dtv * xv;
      float pw[17];
      pw[1] = exp2f(dtv * a2b);
#pragma unroll
      for (int n = 2; n <= 16; ++n) pw[n] = pw[n >> 1] * pw[n - (n >> 1)];
      float4 bq[4], cq[4];
#pragma unroll
      for (int q = 0; q < 4; ++q) {
        bq[q] = *(const float4*)&lBC[tt * 32 + q * 4];
        cq[q] = *(const float4*)&lBC[tt * 32 + 16 + q * 4];
      }
      float ya = 0.f, yb = 0.f;
#pragma unroll
      for (int n = 0; n < 16; ++n) {
        h[n] = h[n] * pw[n + 1] + dtx * (&bq[n >> 2].x)[n & 3];
        const float t2 = h[n] * (&cq[n >> 2].x)[n & 3];
        if (n & 1) yb += t2; else ya += t2;
      }
      const float y = ya + yb + Dd * xv;
      const float zc = cw[0] * zm1 + cw[1] * z0 + cw[2] * zp1 + cw[3] * zp2;
      const float zs = zc / (1.f + __expf(-zc));
      dtyg[r * 384 + d] = __float2bfloat16(y * zs);
      zm1 = z0; z0 = zp1; zp1 = zp2;
    }
  } else {                                 // generic A fallback
    float a2[16];
#pragma unroll
    for (int n = 0; n < 16; ++n) a2[n] = a2f[d * 16 + n];
    for (int tt = 0; tt < tmax; ++tt) {
      const int t = t0 + tt;
      const size_t r = (size_t)(r0 + tt);
      const float zp2 = (t + 2 < L_) ? bf(zh[(r + 2) * 384 + d]) : 0.f;
      const float dtv = bf(dtyg[r * 384 + d]);
      const float xv  = bf(xc[r * 384 + d]);
      const float dtx = dtv * xv;
      float4 bq[4], cq[4];
#pragma unroll
      for (int q = 0; q < 4; ++q) {
        bq[q] = *(const float4*)&lBC[tt * 32 + q * 4];
        cq[q] = *(const float4*)&lBC[tt * 32 + 16 + q * 4];
      }
      float ya = 0.f, yb = 0.f;
#pragma unroll
      for (int n = 0; n < 16; ++n) {
        h[n] = h[n] * exp2f(dtv * a2[n]) + dtx * (&bq[n >> 2].x)[n & 3];
        const float t2 = h[n] * (&cq[n >> 2].x)[n & 3];
        if (n & 1) yb += t2; else ya += t2;
      }
      const float y = ya + yb + Dd * xv;
      const float zc = cw[0] * zm1 + cw[1] * z0 + cw[2] * zp1 + cw[3] * zp2;
      const float zs = zc / (1.f + __expf(-zc));
      dtyg[r * 384 + d] = __float2bfloat16(y * zs);
      zm1 = z0; z0 = zp1; zp1 = zp2;
    }
  }
}

// ---------------------------------------------------------------------------
extern "C" void kernel_launch(void* const* d_in, const int* in_sizes, int n_in,
                              void* d_out, int out_size, void* d_ws, size_t ws_size,
                              hipStream_t stream) {
  const void* hs   = d_in[0];
  const void* w_in = d_in[1];
  const void* cxw  = d_in[2];
  const void* czw  = d_in[3];
  const void* xw   = d_in[4];
  const void* dtw  = d_in[5];
  const void* dtb  = d_in[6];
  const void* alog = d_in[7];
  const void* dpar = d_in[8];
  const void* ow   = d_in[9];
  const int* perm  = (const int*)d_in[10];
  const int* permr = (const int*)d_in[11];

  char* ws = (char*)d_ws;
  size_t off = 0;
  auto alloc = [&](size_t nbytes) -> char* {
    char* p = ws + off;
    off += (nbytes + 255) & ~(size_t)255;
    return p;
  };
  int* flag              = (int*)alloc(256);
  int* nperm             = (int*)alloc(4096 * 4);
  int* npermr            = (int*)alloc(4096 * 4);
  float* a2f             = (float*)alloc(6144 * 4);
  __hip_bfloat16* w_inb  = (__hip_bfloat16*)alloc(294912 * 2);
  __hip_bfloat16* cxwb   = (__hip_bfloat16*)alloc(1536 * 2);
  __hip_bfloat16* czwb   = (__hip_bfloat16*)alloc(1536 * 2);
  __hip_bfloat16* xwb    = (__hip_bfloat16*)alloc(21504 * 2);
  __hip_bfloat16* dtwb   = (__hip_bfloat16*)alloc(9216 * 2);
  __hip_bfloat16* dtbb   = (__hip_bfloat16*)alloc(384 * 2);
  __hip_bfloat16* dparb  = (__hip_bfloat16*)alloc(384 * 2);
  __hip_bfloat16* owb    = (__hip_bfloat16*)alloc(147456 * 2);
  __hip_bfloat16* wcombb = (__hip_bfloat16*)alloc((size_t)512 * 384 * 2);
  __hip_bfloat16* hsb    = (__hip_bfloat16*)alloc((size_t)MTOT * 384 * 2);  // 25.2 MB
  __hip_bfloat16* zh     = (__hip_bfloat16*)alloc((size_t)MTOT * 384 * 2);  // 25.2 MB
  __hip_bfloat16* xc     = (__hip_bfloat16*)alloc((size_t)MTOT * 384 * 2);  // 25.2 MB
  __hip_bfloat16* dtyg   = (__hip_bfloat16*)alloc((size_t)MTOT * 384 * 2);  // 25.2 MB
  float*          bcf    = (float*)alloc((size_t)MTOT * 32 * 4);            // 4.2 MB
  // d_out (50.35 MB) as scratch: xh bf16 [0,25.2) dies at convx; then
  // sdtc fp32 [0, 2.30MB) + hend/hstart fp32 [2.30, 39.06) at NCH=187.
  __hip_bfloat16* xh   = (__hip_bfloat16*)d_out;
  float*          sdtc = (float*)d_out;
  float*          hend = (float*)((char*)d_out + (size_t)NCH * B_ * DH * 4);

  // 0) dtype + perm + A-structure normalization
  flag_k<<<1, 64, 0, stream>>>(hs, flag);
  perm_k<<<2, 1024, 0, stream>>>(perm, permr, nperm, npermr);
  a2prep_k<<<1, 384, 0, stream>>>(alog, a2f, flag);
  NormSet ns;
  ns.src[0] = w_in; ns.dst[0] = w_inb; ns.n[0] = 294912;
  ns.src[1] = ow;   ns.dst[1] = owb;   ns.n[1] = 147456;
  ns.src[2] = xw;   ns.dst[2] = xwb;   ns.n[2] = 21504;
  ns.src[3] = dtw;  ns.dst[3] = dtwb;  ns.n[3] = 9216;
  ns.src[4] = cxw;  ns.dst[4] = cxwb;  ns.n[4] = 1536;
  ns.src[5] = czw;  ns.dst[5] = czwb;  ns.n[5] = 1536;
  ns.src[6] = dtb;  ns.dst[6] = dtbb;  ns.n[6] = 384;
  ns.src[7] = dpar; ns.dst[7] = dparb; ns.n[7] = 384;
  norm_all<<<1152, 256, 0, stream>>>(ns, flag);
  // 1) fused dt/BC weight build
  prep_k<<<768, 256, 0, stream>>>(dtwb, xwb, wcombb);
  // 2) fused perm-gather + bf16 convert of hidden_states
  cvt_k<<<(MTOT * 48 + 255) / 256, 256, 0, stream>>>(hs, hsb, nperm, flag);
  // 3) in_proj MFMA GEMM -> xh (d_out), zh
  gemm_k<0, 0><<<dim3(6, 257), 256, 0, stream>>>(
      hsb, w_inb, xh, zh, nullptr, nullptr, flag, MTOT, 768);
  // 4) depthwise conv + silu on x half (8 ch/thread)
  convx_k<<<(MTOT * 48 + 255) / 256, 256, 0, stream>>>(xh, cxwb, xc);
  // 5) fused dt (bias+fast-softplus, bf16) and B/C (fp32) MFMA GEMM
  gemm_k<0, 1><<<dim3(4, 257), 256, 0, stream>>>(
      xc, wcombb, dtyg, bcf, dtbb, nullptr, flag, MTOT, 512);
  // 6) chunked selective scan: summaries -> cross-chunk -> true recurrence
  scan1_k<<<B_ * NCH * 3, 128, 0, stream>>>(dtyg, bcf, xc, a2f, sdtc, hend, flag);
  scan2_k<<<192, 256, 0, stream>>>(sdtc, hend, a2f);
  scan3_k<<<B_ * NCH * 3, 128, 0, stream>>>(
      dtyg, bcf, xc, zh, czwb, dparb, a2f, hend, flag);
  // 7) out_proj MFMA GEMM with inverse-perm gather -> final output
  gemm_k<1, 2><<<dim3(3, 257), 256, 0, stream>>>(
      dtyg, owb, d_out, nullptr, nullptr, npermr, flag, MTOT, 384);
  (void)in_sizes; (void)n_in; (void)out_size; (void)ws_size;
}

// Round 8
// 332.319 us; speedup vs baseline: 1.1009x; 1.1009x over previous
//
#include <hip/hip_runtime.h>
#include <hip/hip_bf16.h>

#define DEVI __device__ __forceinline__

constexpr int B_   = 8;
constexpr int L_   = 4097;
constexpr int MTOT = B_ * L_;          // 32776 tokens
constexpr int DH   = 384;              // d_half
constexpr int NS   = 16;               // d_state
constexpr int CH   = 33;               // scan chunk (r16: revert to r6's 33;
                                       // r7's CH=22 true-recurrence regressed)
constexpr int NCH  = (L_ + CH - 1) / CH;  // 125 chunks (last has 5 tokens)

typedef __bf16 bf16x8 __attribute__((ext_vector_type(8)));
typedef float  f32x4  __attribute__((ext_vector_type(4)));

DEVI float bl(unsigned v) { return __uint_as_float(v << 16); }          // low bf16
DEVI float bh(unsigned v) { return __uint_as_float(v & 0xffff0000u); }  // high bf16
DEVI float bf(const __hip_bfloat16 x) { return __bfloat162float(x); }
DEVI unsigned short f2bu(float x) {
  __hip_bfloat16 b = __float2bfloat16(x);
  return *(unsigned short*)&b;
}
DEVI float u16f(const uint4& u, int j) {   // element j (0..7) of 8 packed bf16
  const unsigned w = (&u.x)[j >> 1];
  return (j & 1) ? bh(w) : bl(w);
}
// fast softplus: 2 HW transcendentals vs log1pf's ~30-instr libm sequence
DEVI float softplus_f(float x) {
  return (x > 20.f) ? x : __logf(1.f + __expf(x));
}

// global -> LDS direct (16B per lane). LDS dest must be wave-uniform + lane*16.
DEVI void gld16(const __hip_bfloat16* g, __hip_bfloat16* l) {
  __builtin_amdgcn_global_load_lds(
      (const __attribute__((address_space(1))) void*)g,
      (__attribute__((address_space(3))) void*)l, 16, 0, 0);
}

// ---------------------------------------------------------------------------
// dtype detector; flag[1] = geometric-A structure flag.
// ---------------------------------------------------------------------------
__global__ void flag_k(const void* hs, int* flagp) {
  if (threadIdx.x == 0 && blockIdx.x == 0) {
    const unsigned short* u = (const unsigned short*)hs;
    int ok = 1;
    for (int i = 0; i < 8; ++i) {
      const unsigned short v = u[2 * i];
      const int e = (v >> 7) & 0xFF;
      if (!(v == 0 || (e >= 100 && e <= 140))) ok = 0;
    }
    flagp[0] = ok;
    flagp[1] = 1;
  }
}

// ---------------------------------------------------------------------------
// a2prep_k: a2[d][n] = -log2(e)*exp(A_log[d][n]) fp32 + geometric check.
// ---------------------------------------------------------------------------
__global__ void a2prep_k(const void* __restrict__ alog, float* __restrict__ a2fo,
                         int* flagp) {
  const int d = threadIdx.x;             // 384 threads, one d each
  const int f = flagp[0];
  float a2[16];
#pragma unroll
  for (int n = 0; n < 16; ++n) {
    const float v = f ? bf(((const __hip_bfloat16*)alog)[d * 16 + n])
                      : ((const float*)alog)[d * 16 + n];
    a2[n] = -1.4426950408889634f * __expf(v);
    a2fo[d * 16 + n] = a2[n];
  }
  int ok = 1;
#pragma unroll
  for (int n = 1; n < 16; ++n) {
    const float ref = (float)(n + 1) * a2[0];
    if (fabsf(a2[n] - ref) > 1e-3f * fabsf(ref)) ok = 0;
  }
  if (!ok) atomicAnd(&flagp[1], 0);
}

// ---------------------------------------------------------------------------
// perm normalizer: int64 storage has all odd int32 words zero (values<4096).
// ---------------------------------------------------------------------------
__global__ void perm_k(const int* p0, const int* p1, int* d0, int* d1) {
  __shared__ int s_or;
  const int* src = blockIdx.x ? p1 : p0;
  int*       dst = blockIdx.x ? d1 : d0;
  if (threadIdx.x == 0) s_or = 0;
  __syncthreads();
  int loc = 0;
  for (int i = threadIdx.x; i < 2048; i += 1024) loc |= src[2 * i + 1];
  atomicOr(&s_or, loc);
  __syncthreads();
  const bool is64 = (s_or == 0);
  for (int j = threadIdx.x; j < 4096; j += 1024)
    dst[j] = is64 ? (int)((const long long*)src)[j] : src[j];
}

// ---------------------------------------------------------------------------
// fused normalization of weight tensors to bf16 (one launch)
// ---------------------------------------------------------------------------
struct NormSet { const void* src[8]; void* dst[8]; int n[8]; };
__global__ void norm_all(NormSet s, const int* flagp) {
  const int idx = blockIdx.x * 256 + threadIdx.x;
  const int f = flagp[0];
#pragma unroll
  for (int t = 0; t < 8; ++t) {
    if (idx < s.n[t]) {
      __hip_bfloat16* d = (__hip_bfloat16*)s.dst[t];
      if (f) d[idx] = ((const __hip_bfloat16*)s.src[t])[idx];
      else   d[idx] = __float2bfloat16(((const float*)s.src[t])[idx]);
    }
  }
}

// ---------------------------------------------------------------------------
// Wcomb bf16 (512 x 384): rows 0..383 = dt_proj_w @ x_proj_w[0:24],
// rows 384..415 = x_proj_w[24:56] (B then C), rows 416..511 = 0.
// ---------------------------------------------------------------------------
__global__ void prep_k(const __hip_bfloat16* __restrict__ dtw,
                       const __hip_bfloat16* __restrict__ xw,
                       __hip_bfloat16* __restrict__ wcomb) {
  const int idx = blockIdx.x * 256 + threadIdx.x;
  if (idx >= 512 * 384) return;
  const int n = idx / 384, k = idx - n * 384;
  float v = 0.f;
  if (n < 384) {
#pragma unroll
    for (int r = 0; r < 24; ++r) v += bf(dtw[n * 24 + r]) * bf(xw[r * 384 + k]);
  } else if (n < 416) {
    v = bf(xw[(24 + n - 384) * 384 + k]);
  }
  wcomb[idx] = __float2bfloat16(v);
}

// ---------------------------------------------------------------------------
// cvt_k: fused perm-gather + dtype-normalize of hidden_states into bf16 hsb.
// ---------------------------------------------------------------------------
__global__ void cvt_k(const void* __restrict__ hs, __hip_bfloat16* __restrict__ dst,
                      const int* __restrict__ gidx, const int* __restrict__ flagp) {
  const int idx = blockIdx.x * 256 + threadIdx.x;
  if (idx >= MTOT * 48) return;
  const int j = idx % 48;        // 8-elem group within row
  const int r = idx / 48;        // destination (reordered) token row
  const int b = r / L_, t = r - b * L_;
  const int src = b * L_ + (t == 0 ? 0 : 1 + gidx[t - 1]);
  uint4 o;
  if (flagp[0]) {
    o = *(const uint4*)((const __hip_bfloat16*)hs + (size_t)src * 384 + j * 8);
  } else {
    const float* f = (const float*)hs + (size_t)src * 384 + j * 8;
    const float4 f0 = *(const float4*)f;
    const float4 f1 = *(const float4*)(f + 4);
    o.x = f2bu(f0.x) | ((unsigned)f2bu(f0.y) << 16);
    o.y = f2bu(f0.z) | ((unsigned)f2bu(f0.w) << 16);
    o.z = f2bu(f1.x) | ((unsigned)f2bu(f1.y) << 16);
    o.w = f2bu(f1.z) | ((unsigned)f2bu(f1.w) << 16);
  }
  *(uint4*)(dst + (size_t)r * 384 + j * 8) = o;
}

// ---------------------------------------------------------------------------
// MFMA GEMM: 128x128 tile, K=384 = 6 x BK64, staging via global_load_lds w=16
// into [kh][128][32] LDS layout. Epilogue via LDS-transposed 2-pass coalesced
// 16B stores. Bijective XCD-contiguous tile remap.
// ---------------------------------------------------------------------------
template<int GATHER, int EPI>
__global__ __launch_bounds__(256, 3)
void gemm_k(const __hip_bfloat16* __restrict__ A, const __hip_bfloat16* __restrict__ W,
            void* __restrict__ e0, void* __restrict__ e1,
            const __hip_bfloat16* __restrict__ bias,
            const int* __restrict__ gidx, const int* __restrict__ flagp,
            int M, int N)
{
  __shared__ __align__(16) char smem[36864];   // staging 32KB | lT 18.4/36.9KB
  __hip_bfloat16* lA = (__hip_bfloat16*)smem;  // [2][128][32] bf16
  __hip_bfloat16* lB = lA + 2 * 128 * 32;
  const int tid  = threadIdx.x;
  const int lane = tid & 63;
  const int wv   = tid >> 6;
  const int wm   = wv >> 1, wn = wv & 1;
  const int lrow = lane & 15, quad = lane >> 4;
  const int fbf  = flagp[0];              // 1 = bf16 external storage

  const int NT = gridDim.x;
  const int nblocks = NT * (int)gridDim.y;
  const int id = blockIdx.y * NT + blockIdx.x;
  const int q8 = nblocks >> 3, r8 = nblocks & 7;
  const int xcd = id & 7, slot = id >> 3;
  const int nid = (xcd < r8 ? xcd * (q8 + 1)
                            : r8 * (q8 + 1) + (xcd - r8) * q8) + slot;
  const int mt = nid / NT, nt = nid - mt * NT;

  // wave whose whole 64-col band is Wcomb zero-pad: skip fragment+MFMA work
  const bool live = !(EPI == 1 && nt * 128 + wn * 64 >= 416);

  // staging map: flat 16B slot s -> (kh = s>>9, row = (s>>2)&127, c = s&3);
  // LDS dest linear in s (gld_lds constraint); global src permuted to match.
  const __hip_bfloat16* aSrc[4];
  const __hip_bfloat16* bSrc[4];
  __hip_bfloat16* aDst[4];
  __hip_bfloat16* bDst[4];
#pragma unroll
  for (int p = 0; p < 4; ++p) {
    const int s   = p * 256 + tid;
    const int kh  = s >> 9;
    const int row = (s >> 2) & 127;
    const int kc  = kh * 32 + (s & 3) * 8;   // K offset within BK=64
    int r = mt * 128 + row;
    if (r >= M) r = M - 1;                   // tail tile: duplicate a valid row
    int src;
    if (GATHER) { const int b = r / L_, t = r - b * L_;
                  src = b * L_ + (t == 0 ? 0 : 1 + gidx[t - 1]); }
    else        { src = r; }
    aSrc[p] = A + (size_t)src * 384 + kc;
    bSrc[p] = W + (size_t)(nt * 128 + row) * 384 + kc;
    aDst[p] = &lA[s * 8];
    bDst[p] = &lB[s * 8];
  }

  f32x4 acc[4][4] = {};

#pragma unroll
  for (int kt = 0; kt < 6; ++kt) {         // K = 6 * 64
    __syncthreads();                       // WAR: prior ds_reads done
#pragma unroll
    for (int p = 0; p < 4; ++p) gld16(aSrc[p] + kt * 64, aDst[p]);
#pragma unroll
    for (int p = 0; p < 4; ++p) gld16(bSrc[p] + kt * 64, bDst[p]);
    __syncthreads();                       // staged data visible
    if (live) {
#pragma unroll
      for (int kh = 0; kh < 2; ++kh) {
        bf16x8 af[4], bfr[4];
#pragma unroll
        for (int i = 0; i < 4; ++i)
          af[i] = *reinterpret_cast<const bf16x8*>(
              &lA[kh * 4096 + (wm * 64 + i * 16 + lrow) * 32 + quad * 8]);
#pragma unroll
        for (int j = 0; j < 4; ++j)
          bfr[j] = *reinterpret_cast<const bf16x8*>(
              &lB[kh * 4096 + (wn * 64 + j * 16 + lrow) * 32 + quad * 8]);
#pragma unroll
        for (int i = 0; i < 4; ++i)
#pragma unroll
          for (int j = 0; j < 4; ++j)
            acc[i][j] = __builtin_amdgcn_mfma_f32_16x16x32_bf16(af[i], bfr[j], acc[i][j], 0, 0, 0);
      }
    }
  }

  // ---- epilogue (acc[i][j][rg] = C[row=quad*4+rg(+i*16+wm*64)][col=lrow(+j*16+wn*64)])
  const int r0c = mt * 128;
  if (EPI == 1 && nt == 3) {
    // scalar B/C path (cols 384..415, fp32)
#pragma unroll
    for (int i = 0; i < 4; ++i) {
      const int row0 = r0c + wm * 64 + i * 16 + quad * 4;
#pragma unroll
      for (int j = 0; j < 4; ++j) {
        const int col = 384 + wn * 64 + j * 16 + lrow;
        if (col >= 416) continue;
#pragma unroll
        for (int rg = 0; rg < 4; ++rg) {
          const int r = row0 + rg;
          if (r >= M) continue;
          ((float*)e1)[(size_t)r * 32 + (col - 384)] = acc[i][j][rg];
        }
      }
    }
  } else if (EPI == 2 && !fbf) {
    // fp32 out: 2-pass LDS transpose ([128][72] f32), coalesced 16B stores
    float* lT = (float*)smem;
#pragma unroll
    for (int h = 0; h < 2; ++h) {
      __syncthreads();
      if (wn == h) {
#pragma unroll
        for (int i = 0; i < 4; ++i)
#pragma unroll
          for (int j = 0; j < 4; ++j)
#pragma unroll
            for (int rg = 0; rg < 4; ++rg)
              lT[(wm * 64 + i * 16 + quad * 4 + rg) * 72 + j * 16 + lrow] = acc[i][j][rg];
      }
      __syncthreads();
#pragma unroll
      for (int p = 0; p < 8; ++p) {
        const int ch = p * 256 + tid;      // 2048 x 16B chunks
        const int row = ch >> 4, c4 = (ch & 15) * 4;
        const int r = r0c + row;
        if (r < M) {
          const float4 v = *(const float4*)&lT[row * 72 + c4];
          *(float4*)((float*)e0 + (size_t)r * 384 + nt * 128 + h * 64 + c4) = v;
        }
      }
    }
  } else {
    // bf16: 2-pass LDS transpose ([128][72] bf16), coalesced 16B stores.
    // EPI=0 plain; EPI=1 nt<3 softplus+bias; EPI=2 fbf plain.
    __hip_bfloat16* lT = (__hip_bfloat16*)smem;
#pragma unroll
    for (int h = 0; h < 2; ++h) {
      __syncthreads();
      if (wn == h) {
        float bj[4] = {};
        if (EPI == 1) {
#pragma unroll
          for (int j = 0; j < 4; ++j)
            bj[j] = bf(bias[nt * 128 + h * 64 + j * 16 + lrow]);
        }
#pragma unroll
        for (int i = 0; i < 4; ++i)
#pragma unroll
          for (int j = 0; j < 4; ++j)
#pragma unroll
            for (int rg = 0; rg < 4; ++rg) {
              float v = acc[i][j][rg];
              if (EPI == 1) v = softplus_f(v + bj[j]);
              lT[(wm * 64 + i * 16 + quad * 4 + rg) * 72 + j * 16 + lrow] =
                  __float2bfloat16(v);
            }
      }
      __syncthreads();
#pragma unroll
      for (int p = 0; p < 4; ++p) {
        const int ch = p * 256 + tid;      // 1024 x 16B chunks
        const int row = ch >> 3, c8 = (ch & 7) * 8;
        const int r = r0c + row;
        if (r < M) {
          const uint4 v = *(const uint4*)&lT[row * 72 + c8];
          const int g = nt * 128 + h * 64 + c8;
          __hip_bfloat16* dst = (EPI == 0 && g >= 384)
                ? (__hip_bfloat16*)e1 + (size_t)r * 384 + (g - 384)
                : (__hip_bfloat16*)e0 + (size_t)r * 384 + g;
          *(uint4*)dst = v;
        }
      }
    }
  }
}

// ---------------------------------------------------------------------------
// depthwise conv k=4 (taps t-1..t+2) + silu on x half; 8 channels/thread.
// ---------------------------------------------------------------------------
__global__ void convx_k(const __hip_bfloat16* __restrict__ xh,
                        const __hip_bfloat16* __restrict__ cxw,
                        __hip_bfloat16* __restrict__ xc) {
  const int idx = blockIdx.x * 256 + threadIdx.x;
  if (idx >= MTOT * 48) return;
  const int g  = idx % 48;       // channel group (8 ch)
  const int rg = idx / 48;       // token row
  const int t  = rg % L_;
  const int c0 = g * 8;
  uint4 wv[4];                   // weights: channels c0..c0+7 x 4 taps
#pragma unroll
  for (int p = 0; p < 4; ++p) wv[p] = *(const uint4*)(cxw + c0 * 4 + p * 8);
  float acc[8] = {};
#pragma unroll
  for (int k = 0; k < 4; ++k) {
    const int tt = t + k - 1;
    if (tt < 0 || tt >= L_) continue;
    const uint4 u = *(const uint4*)(xh + (size_t)(rg + k - 1) * 384 + c0);
#pragma unroll
    for (int j = 0; j < 8; ++j) {
      const int e = j * 4 + k;                      // weight flat element
      acc[j] += u16f(wv[e >> 3], e & 7) * u16f(u, j);
    }
  }
  uint4 o;
#pragma unroll
  for (int p = 0; p < 4; ++p) {
    const float s0 = acc[2 * p]     / (1.f + __expf(-acc[2 * p]));
    const float s1 = acc[2 * p + 1] / (1.f + __expf(-acc[2 * p + 1]));
    (&o.x)[p] = f2bu(s0) | ((unsigned)f2bu(s1) << 16);
  }
  *(uint4*)(xc + (size_t)rg * 384 + c0) = o;
}

// ---------------------------------------------------------------------------
// scan phase 1 (r16 = r6 + prefetch): per (b, chunk, d) local scan with
// h0=0, y_local written IN PLACE over xc. The in-place store creates a false
// store->load dependence the compiler can't break (xcio aliases dt's array
// class); MANUAL one-iteration prefetch of dt[t+1], x[t+1] issues the loads
// ~1 body (~180 cyc) early, covering L2 latency (r6 counters: VALUBusy 46%,
// latency-stalled).
// ---------------------------------------------------------------------------
__global__ __launch_bounds__(128)
void scan1_k(const __hip_bfloat16* __restrict__ dt, const float* __restrict__ bc,
             __hip_bfloat16* xcio,
             const float* __restrict__ a2f,
             const __hip_bfloat16* __restrict__ dpar,
             float* __restrict__ pbuf, float* __restrict__ hend,
             const int* __restrict__ flagp)
{
  __shared__ __align__(16) float lBC[CH * 32];
  const int blk = blockIdx.x;
  const int dt3 = blk % 3;
  const int c   = (blk / 3) % NCH;
  const int b   = blk / (3 * NCH);
  const int d   = dt3 * 128 + threadIdx.x;
  const int t0  = c * CH;
  const int r0  = b * L_ + t0;
  const int tmax = (L_ - t0 < CH) ? (L_ - t0) : CH;
  for (int i = threadIdx.x; i < tmax * 32; i += 128) lBC[i] = bc[(size_t)r0 * 32 + i];
  __syncthreads();

  float h[16];
#pragma unroll
  for (int n = 0; n < 16; ++n) h[n] = 0.f;
  float sdt = 0.f;
  const float Dd = bf(dpar[d]);
  const size_t base = ((size_t)(c * 8 + b) * 16) * 384 + d;

  float dtv = bf(dt[(size_t)r0 * 384 + d]);
  float xv  = bf(xcio[(size_t)r0 * 384 + d]);

  if (flagp[1]) {                          // geometric A: a2[n] = (n+1)*a2b
    const float a2b = a2f[d * 16];
    for (int tt = 0; tt < tmax; ++tt) {
      const size_t r = (size_t)(r0 + tt);
      float dtv_n = 0.f, xv_n = 0.f;
      if (tt + 1 < tmax) {                 // prefetch BEFORE the in-place store
        dtv_n = bf(dt[(r + 1) * 384 + d]);
        xv_n  = bf(xcio[(r + 1) * 384 + d]);
      }
      sdt += dtv;
      const float dtx = dtv * xv;
      float pw[17];
      pw[1] = exp2f(dtv * a2b);
#pragma unroll
      for (int n = 2; n <= 16; ++n) pw[n] = pw[n >> 1] * pw[n - (n >> 1)];
      float4 bq[4], cq[4];
#pragma unroll
      for (int q = 0; q < 4; ++q) {
        bq[q] = *(const float4*)&lBC[tt * 32 + q * 4];
        cq[q] = *(const float4*)&lBC[tt * 32 + 16 + q * 4];
      }
      float ya = 0.f, yb = 0.f;
#pragma unroll
      for (int n = 0; n < 16; ++n) {
        h[n] = h[n] * pw[n + 1] + dtx * (&bq[n >> 2].x)[n & 3];
        const float t = h[n] * (&cq[n >> 2].x)[n & 3];
        if (n & 1) yb += t; else ya += t;
      }
      const float y = ya + yb + Dd * xv;
      xcio[r * 384 + d] = __float2bfloat16(y);
      dtv = dtv_n; xv = xv_n;
    }
    float Ep[17];
    Ep[1] = exp2f(sdt * a2b);
#pragma unroll
    for (int n = 2; n <= 16; ++n) Ep[n] = Ep[n >> 1] * Ep[n - (n >> 1)];
#pragma unroll
    for (int n = 0; n < 16; ++n) {
      pbuf[base + n * 384] = Ep[n + 1];
      hend[base + n * 384] = h[n];
    }
  } else {                                 // generic A fallback
    float a2[16];
#pragma unroll
    for (int n = 0; n < 16; ++n) a2[n] = a2f[d * 16 + n];
    for (int tt = 0; tt < tmax; ++tt) {
      const size_t r = (size_t)(r0 + tt);
      float dtv_n = 0.f, xv_n = 0.f;
      if (tt + 1 < tmax) {
        dtv_n = bf(dt[(r + 1) * 384 + d]);
        xv_n  = bf(xcio[(r + 1) * 384 + d]);
      }
      sdt += dtv;
      const float dtx = dtv * xv;
      float4 bq[4], cq[4];
#pragma unroll
      for (int q = 0; q < 4; ++q) {
        bq[q] = *(const float4*)&lBC[tt * 32 + q * 4];
        cq[q] = *(const float4*)&lBC[tt * 32 + 16 + q * 4];
      }
      float ya = 0.f, yb = 0.f;
#pragma unroll
      for (int n = 0; n < 16; ++n) {
        h[n] = h[n] * exp2f(dtv * a2[n]) + dtx * (&bq[n >> 2].x)[n & 3];
        const float t = h[n] * (&cq[n >> 2].x)[n & 3];
        if (n & 1) yb += t; else ya += t;
      }
      const float y = ya + yb + Dd * xv;
      xcio[r * 384 + d] = __float2bfloat16(y);
      dtv = dtv_n; xv = xv_n;
    }
#pragma unroll
    for (int n = 0; n < 16; ++n) {
      pbuf[base + n * 384] = exp2f(sdt * a2[n]);
      hend[base + n * 384] = h[n];
    }
  }
}

// ---------------------------------------------------------------------------
// scan phase 2: cross-chunk scan per (b,d,n); rewrites pbuf with h_start
// ---------------------------------------------------------------------------
__global__ void scan2_k(float* __restrict__ pbuf, const float* __restrict__ hend) {
  const int tid = blockIdx.x * 256 + threadIdx.x;   // 49152 total
  const int d = tid % 384;
  const int n = (tid / 384) & 15;
  const int b = tid / 6144;
  float H = 0.f;
  for (int c = 0; c < NCH; ++c) {
    const size_t idx = ((size_t)(c * 8 + b) * 16 + n) * 384 + d;
    const float p = pbuf[idx];
    const float he = hend[idx];
    pbuf[idx] = H;
    H = p * H + he;
  }
}

// ---------------------------------------------------------------------------
// scan phase 3 (r16 = r6 + prefetch): y(t) = y_local(t) + corr; fused z-conv
// + silu gate; IN PLACE over dt (dtyg). Manual prefetch of dtyg[t+1] and
// yl[t+1] before the in-place store (same false-dependence fix as scan1).
// ---------------------------------------------------------------------------
__global__ __launch_bounds__(128)
void scan3_k(__hip_bfloat16* dtyg, const float* __restrict__ bc,
             const __hip_bfloat16* __restrict__ yl,
             const __hip_bfloat16* __restrict__ zh,
             const __hip_bfloat16* __restrict__ czw,
             const float* __restrict__ a2f,
             const float* __restrict__ hstart,
             const int* __restrict__ flagp)
{
  __shared__ __align__(16) float lC[CH * 16];
  const int blk = blockIdx.x;
  const int dt3 = blk % 3;
  const int c   = (blk / 3) % NCH;
  const int b   = blk / (3 * NCH);
  const int d   = dt3 * 128 + threadIdx.x;
  const int t0  = c * CH;
  const int r0  = b * L_ + t0;
  const int tmax = (L_ - t0 < CH) ? (L_ - t0) : CH;
  for (int i = threadIdx.x; i < tmax * 16; i += 128)
    lC[i] = bc[(size_t)r0 * 32 + (i >> 4) * 32 + 16 + (i & 15)];
  __syncthreads();

  float hs_[16];
  const size_t base = ((size_t)(c * 8 + b) * 16) * 384 + d;
#pragma unroll
  for (int n = 0; n < 16; ++n) hs_[n] = hstart[base + n * 384];
  float cw[4];
#pragma unroll
  for (int k = 0; k < 4; ++k) cw[k] = bf(czw[d * 4 + k]);

  float zm1 = (t0 - 1 >= 0) ? bf(zh[(size_t)(r0 - 1) * 384 + d]) : 0.f;
  float z0  = bf(zh[(size_t)r0 * 384 + d]);
  float zp1 = (t0 + 1 < L_) ? bf(zh[(size_t)(r0 + 1) * 384 + d]) : 0.f;
  float sdt = 0.f;

  float dtv = bf(dtyg[(size_t)r0 * 384 + d]);
  float ylv = bf(yl[(size_t)r0 * 384 + d]);

  if (flagp[1]) {                          // geometric A fast path
    const float a2b = a2f[d * 16];
    for (int tt = 0; tt < tmax; ++tt) {
      const int t = t0 + tt;
      const size_t r = (size_t)(r0 + tt);
      const float zp2 = (t + 2 < L_) ? bf(zh[(r + 2) * 384 + d]) : 0.f;
      float dtv_n = 0.f, ylv_n = 0.f;
      if (tt + 1 < tmax) {                 // prefetch BEFORE the in-place store
        dtv_n = bf(dtyg[(r + 1) * 384 + d]);
        ylv_n = bf(yl[(r + 1) * 384 + d]);
      }
      sdt += dtv;
      float pw[17];
      pw[1] = exp2f(sdt * a2b);
#pragma unroll
      for (int n = 2; n <= 16; ++n) pw[n] = pw[n >> 1] * pw[n - (n >> 1)];
      float4 cq[4];
#pragma unroll
      for (int q = 0; q < 4; ++q) cq[q] = *(const float4*)&lC[tt * 16 + q * 4];
      float ca = 0.f, cb = 0.f;
#pragma unroll
      for (int n = 0; n < 16; ++n) {
        const float t2 = (&cq[n >> 2].x)[n & 3] * hs_[n] * pw[n + 1];
        if (n & 1) cb += t2; else ca += t2;
      }
      const float y = ylv + ca + cb;
      const float zc = cw[0] * zm1 + cw[1] * z0 + cw[2] * zp1 + cw[3] * zp2;
      const float zs = zc / (1.f + __expf(-zc));
      dtyg[r * 384 + d] = __float2bfloat16(y * zs);
      zm1 = z0; z0 = zp1; zp1 = zp2;
      dtv = dtv_n; ylv = ylv_n;
    }
  } else {                                 // generic A fallback
    float a2[16];
#pragma unroll
    for (int n = 0; n < 16; ++n) a2[n] = a2f[d * 16 + n];
    for (int tt = 0; tt < tmax; ++tt) {
      const int t = t0 + tt;
      const size_t r = (size_t)(r0 + tt);
      const float zp2 = (t + 2 < L_) ? bf(zh[(r + 2) * 384 + d]) : 0.f;
      float dtv_n = 0.f, ylv_n = 0.f;
      if (tt + 1 < tmax) {
        dtv_n = bf(dtyg[(r + 1) * 384 + d]);
        ylv_n = bf(yl[(r + 1) * 384 + d]);
      }
      sdt += dtv;
      float4 cq[4];
#pragma unroll
      for (int q = 0; q < 4; ++q) cq[q] = *(const float4*)&lC[tt * 16 + q * 4];
      float ca = 0.f, cb = 0.f;
#pragma unroll
      for (int n = 0; n < 16; ++n) {
        const float t2 = (&cq[n >> 2].x)[n & 3] * hs_[n] * exp2f(sdt * a2[n]);
        if (n & 1) cb += t2; else ca += t2;
      }
      const float y = ylv + ca + cb;
      const float zc = cw[0] * zm1 + cw[1] * z0 + cw[2] * zp1 + cw[3] * zp2;
      const float zs = zc / (1.f + __expf(-zc));
      dtyg[r * 384 + d] = __float2bfloat16(y * zs);
      zm1 = z0; z0 = zp1; zp1 = zp2;
      dtv = dtv_n; ylv = ylv_n;
    }
  }
}

// ---------------------------------------------------------------------------
extern "C" void kernel_launch(void* const* d_in, const int* in_sizes, int n_in,
                              void* d_out, int out_size, void* d_ws, size_t ws_size,
                              hipStream_t stream) {
  const void* hs   = d_in[0];
  const void* w_in = d_in[1];
  const void* cxw  = d_in[2];
  const void* czw  = d_in[3];
  const void* xw   = d_in[4];
  const void* dtw  = d_in[5];
  const void* dtb  = d_in[6];
  const void* alog = d_in[7];
  const void* dpar = d_in[8];
  const void* ow   = d_in[9];
  const int* perm  = (const int*)d_in[10];
  const int* permr = (const int*)d_in[11];

  char* ws = (char*)d_ws;
  size_t off = 0;
  auto alloc = [&](size_t nbytes) -> char* {
    char* p = ws + off;
    off += (nbytes + 255) & ~(size_t)255;
    return p;
  };
  int* flag              = (int*)alloc(256);
  int* nperm             = (int*)alloc(4096 * 4);
  int* npermr            = (int*)alloc(4096 * 4);
  float* a2f             = (float*)alloc(6144 * 4);
  __hip_bfloat16* w_inb  = (__hip_bfloat16*)alloc(294912 * 2);
  __hip_bfloat16* cxwb   = (__hip_bfloat16*)alloc(1536 * 2);
  __hip_bfloat16* czwb   = (__hip_bfloat16*)alloc(1536 * 2);
  __hip_bfloat16* xwb    = (__hip_bfloat16*)alloc(21504 * 2);
  __hip_bfloat16* dtwb   = (__hip_bfloat16*)alloc(9216 * 2);
  __hip_bfloat16* dtbb   = (__hip_bfloat16*)alloc(384 * 2);
  __hip_bfloat16* dparb  = (__hip_bfloat16*)alloc(384 * 2);
  __hip_bfloat16* owb    = (__hip_bfloat16*)alloc(147456 * 2);
  __hip_bfloat16* wcombb = (__hip_bfloat16*)alloc((size_t)512 * 384 * 2);
  __hip_bfloat16* hsb    = (__hip_bfloat16*)alloc((size_t)MTOT * 384 * 2);  // 25.2 MB
  __hip_bfloat16* zh     = (__hip_bfloat16*)alloc((size_t)MTOT * 384 * 2);  // 25.2 MB
  __hip_bfloat16* xc     = (__hip_bfloat16*)alloc((size_t)MTOT * 384 * 2);  // 25.2 MB
  __hip_bfloat16* dtyg   = (__hip_bfloat16*)alloc((size_t)MTOT * 384 * 2);  // 25.2 MB
  float*          bcf    = (float*)alloc((size_t)MTOT * 32 * 4);            // 4.2 MB
  // d_out (50.35 MB) as scratch: xh bf16 [0,25.2) dies at convx; then
  // pbuf [0,24.58) + hend [24.58,49.15) -- NCH=125 sized to fit both.
  __hip_bfloat16* xh   = (__hip_bfloat16*)d_out;
  float*          pbuf = (float*)d_out;
  float*          hend = (float*)((char*)d_out + (size_t)NCH * B_ * NS * DH * 4);

  // 0) dtype + perm + A-structure normalization
  flag_k<<<1, 64, 0, stream>>>(hs, flag);
  perm_k<<<2, 1024, 0, stream>>>(perm, permr, nperm, npermr);
  a2prep_k<<<1, 384, 0, stream>>>(alog, a2f, flag);
  NormSet ns;
  ns.src[0] = w_in; ns.dst[0] = w_inb; ns.n[0] = 294912;
  ns.src[1] = ow;   ns.dst[1] = owb;   ns.n[1] = 147456;
  ns.src[2] = xw;   ns.dst[2] = xwb;   ns.n[2] = 21504;
  ns.src[3] = dtw;  ns.dst[3] = dtwb;  ns.n[3] = 9216;
  ns.src[4] = cxw;  ns.dst[4] = cxwb;  ns.n[4] = 1536;
  ns.src[5] = czw;  ns.dst[5] = czwb;  ns.n[5] = 1536;
  ns.src[6] = dtb;  ns.dst[6] = dtbb;  ns.n[6] = 384;
  ns.src[7] = dpar; ns.dst[7] = dparb; ns.n[7] = 384;
  norm_all<<<1152, 256, 0, stream>>>(ns, flag);
  // 1) fused dt/BC weight build
  prep_k<<<768, 256, 0, stream>>>(dtwb, xwb, wcombb);
  // 2) fused perm-gather + bf16 convert of hidden_states
  cvt_k<<<(MTOT * 48 + 255) / 256, 256, 0, stream>>>(hs, hsb, nperm, flag);
  // 3) in_proj MFMA GEMM -> xh (d_out), zh
  gemm_k<0, 0><<<dim3(6, 257), 256, 0, stream>>>(
      hsb, w_inb, xh, zh, nullptr, nullptr, flag, MTOT, 768);
  // 4) depthwise conv + silu on x half (8 ch/thread)
  convx_k<<<(MTOT * 48 + 255) / 256, 256, 0, stream>>>(xh, cxwb, xc);
  // 5) fused dt (bias+fast-softplus, bf16) and B/C (fp32) MFMA GEMM
  gemm_k<0, 1><<<dim3(4, 257), 256, 0, stream>>>(
      xc, wcombb, dtyg, bcf, dtbb, nullptr, flag, MTOT, 512);
  // 6) chunked selective scan (y_local in phase 1; light correction phase 3)
  scan1_k<<<B_ * NCH * 3, 128, 0, stream>>>(dtyg, bcf, xc, a2f, dparb, pbuf, hend, flag);
  scan2_k<<<192, 256, 0, stream>>>(pbuf, hend);
  scan3_k<<<B_ * NCH * 3, 128, 0, stream>>>(dtyg, bcf, xc, zh, czwb, a2f, pbuf, flag);
  // 7) out_proj MFMA GEMM with inverse-perm gather -> final output
  gemm_k<1, 2><<<dim3(3, 257), 256, 0, stream>>>(
      dtyg, owb, d_out, nullptr, nullptr, npermr, flag, MTOT, 384);
  (void)in_sizes; (void)n_in; (void)out_size; (void)ws_size;
}